// Round 6
// baseline (164.687 us; speedup 1.0000x reference)
//
#include <hip/hip_runtime.h>
#include <hip/hip_bf16.h>

// Problem constants: N tokens, D d_model, E experts, H hidden, K top-k
#define NTOK 4096
#define DM   512
#define NE   32
#define HD   128
#define TK   4

typedef unsigned short u16;
typedef unsigned int   u32;
typedef u16   u16x4 __attribute__((ext_vector_type(4)));
typedef u16   u16x8 __attribute__((ext_vector_type(8)));
typedef short short8 __attribute__((ext_vector_type(8)));
typedef float f32x4 __attribute__((ext_vector_type(4)));

__device__ __forceinline__ u16 f2bf(float f) {
    union { float f; u32 u; } v; v.f = f;
    return (u16)((v.u + 0x7FFFu + ((v.u >> 16) & 1u)) >> 16);   // RNE
}
__device__ __forceinline__ float bf2f(u16 h) {
    union { u32 u; float f; } v; v.u = ((u32)h) << 16; return v.f;
}

// ---------------- weight swizzle (no LDS -> high occupancy, deep ILP) ----------------
// fp32 [E][Kdim][Ndim] -> bf16 fragment-major:
//   frag[wl][lane][j] = in[e][32*ks + (lane>>4)*8 + j][16*nt + (lane&15)]
// W1: Kdim=512, Ndim=128, wl = e*128 + ks*8  + nt  (frags 0..4095)
// W2: Kdim=128, Ndim=512, wl = e*128 + ks*32 + nt  (frags 4096..8191)
__global__ __launch_bounds__(256) void swizzle_kernel(const float* __restrict__ w1,
                                                      const float* __restrict__ w2,
                                                      u16* __restrict__ wf1,
                                                      u16* __restrict__ wf2,
                                                      int* __restrict__ counts) {
    int tid = threadIdx.x;
    if (blockIdx.x == 0 && tid < NE) counts[tid] = 0;   // replaces memset dispatch
    int wv = tid >> 6, lane = tid & 63;
    int m = lane & 15, q = lane >> 4;
    int f0 = (blockIdx.x * 4 + wv) * 2;

    const float* in[2]; u16* outp[2]; int Nd[2];
#pragma unroll
    for (int u = 0; u < 2; ++u) {
        int w = f0 + u;
        if (w < 4096) {
            int e = w >> 7, rem = w & 127, ks = rem >> 3, nt = rem & 7;
            in[u] = w1 + (size_t)e * DM * HD + (size_t)(32 * ks + q * 8) * HD + 16 * nt + m;
            Nd[u] = HD;
            outp[u] = wf1 + (size_t)w * 512 + lane * 8;
        } else {
            int wl = w - 4096, e = wl >> 7, rem = wl & 127, ks = rem >> 5, nt = rem & 31;
            in[u] = w2 + (size_t)e * HD * DM + (size_t)(32 * ks + q * 8) * DM + 16 * nt + m;
            Nd[u] = DM;
            outp[u] = wf2 + (size_t)wl * 512 + lane * 8;
        }
    }
    float v[2][8];
#pragma unroll
    for (int u = 0; u < 2; ++u)
#pragma unroll
        for (int j = 0; j < 8; ++j) v[u][j] = in[u][(size_t)j * Nd[u]];
#pragma unroll
    for (int u = 0; u < 2; ++u) {
        u16x8 h;
#pragma unroll
        for (int j = 0; j < 8; ++j) h[j] = f2bf(v[u][j]);
        *(u16x8*)outp[u] = h;
    }
}

// ---------------- router: 4 tokens/block, thread=(token,expert,K-half) fp64 ----------------
__global__ __launch_bounds__(256) void router_kernel(const float* __restrict__ x,
                                                     const float* __restrict__ sel,
                                                     int* __restrict__ counts,
                                                     int* __restrict__ tok_list,
                                                     float* __restrict__ gate_list,
                                                     u16* __restrict__ xbf) {
    __shared__ float  xs[4][520];                   // 520: 16B-aligned rows, 2-way banks max
    __shared__ double sc[4][33];
    int tid = threadIdx.x;
    int tb = blockIdx.x * 4;

    // stage x (4 x 512) -> LDS fp32, write xbf bf16 on the way
#pragma unroll
    for (int rep = 0; rep < 2; ++rep) {
        int idx = (rep * 256 + tid) * 4;            // element in 4x512 tile
        int row = idx >> 9, col = idx & 511;
        f32x4 v = *(const f32x4*)(x + (size_t)(tb + row) * DM + col);
        *(f32x4*)&xs[row][col] = v;
        u16x4 h;
#pragma unroll
        for (int j = 0; j < 4; ++j) h[j] = f2bf(v[j]);
        *(u16x4*)(xbf + (size_t)(tb + row) * DM + col) = h;
    }
    __syncthreads();

    // thread: tok = tid&3, seg = (tid>>2)&1, e = tid>>3 ; 256-long fp64 dot, 4 chains
    int tok = tid & 3, seg = (tid >> 2) & 1, e = tid >> 3;
    const float* sp = sel + (size_t)e * DM + seg * 256;
    const float* xp = &xs[tok][seg * 256];
    double pa = 0.0, pb = 0.0, pc = 0.0, pd = 0.0;
#pragma unroll 4
    for (int j = 0; j < 256; j += 16) {
        f32x4 x0 = *(const f32x4*)(xp + j);
        f32x4 x1 = *(const f32x4*)(xp + j + 4);
        f32x4 x2 = *(const f32x4*)(xp + j + 8);
        f32x4 x3 = *(const f32x4*)(xp + j + 12);
        f32x4 s0 = *(const f32x4*)(sp + j);
        f32x4 s1 = *(const f32x4*)(sp + j + 4);
        f32x4 s2 = *(const f32x4*)(sp + j + 8);
        f32x4 s3 = *(const f32x4*)(sp + j + 12);
#pragma unroll
        for (int k = 0; k < 4; ++k) {
            pa = fma((double)x0[k], (double)s0[k], pa);
            pb = fma((double)x1[k], (double)s1[k], pb);
            pc = fma((double)x2[k], (double)s2[k], pc);
            pd = fma((double)x3[k], (double)s3[k], pd);
        }
    }
    double p = (pa + pb) + (pc + pd);
    p += __shfl_xor(p, 4);                          // combine the two K-halves (bit2 of tid)
    if (seg == 0) sc[tok][e] = p;
    __syncthreads();

    if (tid < 4) {
        int t = tb + tid;
        unsigned mask = 0;
        for (int k = 0; k < TK; ++k) {
            double best = -1e300; int be = 0;
            for (int ee = 0; ee < NE; ++ee) {
                double v = sc[tid][ee];
                if (!((mask >> ee) & 1u) && v > best) { best = v; be = ee; }
            }
            mask |= 1u << be;
            float gate = 1.0f / (1.0f + __expf(-(float)best));
            int pos = atomicAdd(&counts[be], 1);
            tok_list[(size_t)be * NTOK + pos]  = (k << 16) | t;   // slot in high bits
            gate_list[(size_t)be * NTOK + pos] = gate;
        }
    }
}

// ---------------- fused expert MLP ----------------
// per (expert, 64-token tile); GEMM1 waves split 2x2 (rows x cols), paired-k double
// buffer; GEMM2 each wave owns a distinct 128-col group, all B up-front.
__global__ __launch_bounds__(256, 2) void moe_mlp_kernel(const u16* __restrict__ xbf,
                                                         const u16* __restrict__ wf1,
                                                         const u16* __restrict__ wf2,
                                                         const int* __restrict__ counts,
                                                         const int* __restrict__ tok_list,
                                                         const float* __restrict__ gate_list,
                                                         u16* __restrict__ part,
                                                         float* __restrict__ out,
                                                         int use_part) {
    __shared__ int   s_cnt[NE];
    __shared__ int   s_ent[64];
    __shared__ float s_gate[64];
    __shared__ __align__(16) u16 Hm[64][136];       // 272B stride: 16B-aligned, ~2-way banks

    int tid = threadIdx.x;
    if (tid < NE) s_cnt[tid] = counts[tid];         // one coalesced load, not 32 serial
    __syncthreads();

    int b = blockIdx.x;
    int e = -1, t = 0, rows = 0, pre = 0;
#pragma unroll 8
    for (int ee = 0; ee < NE; ++ee) {
        int cc = s_cnt[ee];
        int nt = (cc + 63) >> 6;
        if (e < 0 && b < pre + nt) { e = ee; t = b - pre; rows = cc - t * 64; if (rows > 64) rows = 64; }
        pre += nt;
    }
    if (e < 0) return;

    if (tid < 64) {
        int base = e * NTOK + t * 64;
        bool val = tid < rows;
        s_ent[tid]  = tok_list[base + (val ? tid : 0)];
        s_gate[tid] = val ? gate_list[base + tid] : 0.0f;
    }
    __syncthreads();

    int wv = tid >> 6, lane = tid & 63, m = lane & 15, q = lane >> 4;
    int r = wv >> 1, c = wv & 1;                    // GEMM1: rows 32r..+32, cols 64c..+64
    const u16* w1f = wf1 + (size_t)e * (128 * 512);
    const u16* w2f = wf2 + (size_t)e * (128 * 512);

    const u16* a0 = xbf + (size_t)(s_ent[32 * r + m] & 0xFFFF) * DM + q * 8;
    const u16* a1 = xbf + (size_t)(s_ent[32 * r + 16 + m] & 0xFFFF) * DM + q * 8;

    // GEMM1: k-steps in pairs, double-buffered (12 loads in flight)
    short8 ab[2][2][2];                             // [buf][kk][mtile]
    short8 bb[2][2][4];                             // [buf][kk][ntile]
#pragma unroll
    for (int kk = 0; kk < 2; ++kk) {
        ab[0][kk][0] = *(const short8*)(a0 + 32 * kk);
        ab[0][kk][1] = *(const short8*)(a1 + 32 * kk);
        const u16* bp = w1f + (size_t)kk * 4096 + (size_t)(4 * c) * 512 + lane * 8;
#pragma unroll
        for (int n = 0; n < 4; ++n) bb[0][kk][n] = *(const short8*)(bp + n * 512);
    }
    f32x4 acc[2][4];
#pragma unroll
    for (int i = 0; i < 2; ++i)
#pragma unroll
        for (int n = 0; n < 4; ++n) acc[i][n] = (f32x4){0.f, 0.f, 0.f, 0.f};

#pragma unroll
    for (int kp = 0; kp < 8; ++kp) {
        int cur = kp & 1, nxt = cur ^ 1;
        if (kp < 7) {
            int ks0 = 2 * (kp + 1);
#pragma unroll
            for (int kk = 0; kk < 2; ++kk) {
                ab[nxt][kk][0] = *(const short8*)(a0 + 32 * (ks0 + kk));
                ab[nxt][kk][1] = *(const short8*)(a1 + 32 * (ks0 + kk));
                const u16* bp = w1f + (size_t)(ks0 + kk) * 4096 + (size_t)(4 * c) * 512 + lane * 8;
#pragma unroll
                for (int n = 0; n < 4; ++n) bb[nxt][kk][n] = *(const short8*)(bp + n * 512);
            }
        }
#pragma unroll
        for (int kk = 0; kk < 2; ++kk)
#pragma unroll
            for (int i = 0; i < 2; ++i)
#pragma unroll
                for (int n = 0; n < 4; ++n)
                    acc[i][n] = __builtin_amdgcn_mfma_f32_16x16x32_bf16(ab[cur][kk][i],
                                                                        bb[cur][kk][n],
                                                                        acc[i][n], 0, 0, 0);
    }

    // relu * gate -> Hm
#pragma unroll
    for (int i = 0; i < 2; ++i) {
        int rb = 32 * r + 16 * i + q * 4;
#pragma unroll
        for (int n = 0; n < 4; ++n)
#pragma unroll
            for (int rr = 0; rr < 4; ++rr)
                Hm[rb + rr][64 * c + 16 * n + m] =
                    f2bf(fmaxf(acc[i][n][rr], 0.f) * s_gate[rb + rr]);
    }

    // GEMM2: wave owns cols [128*wv, 128*wv+128); all 32 B-frags issued before barrier
    short8 cb[4][8];
#pragma unroll
    for (int ks = 0; ks < 4; ++ks) {
        const u16* bp = w2f + (size_t)(ks * 32 + wv * 8) * 512 + lane * 8;
#pragma unroll
        for (int n = 0; n < 8; ++n) cb[ks][n] = *(const short8*)(bp + n * 512);
    }
    __syncthreads();                                // Hm ready

#pragma unroll
    for (int half = 0; half < 2; ++half) {
        f32x4 acc2[2][8];
#pragma unroll
        for (int i = 0; i < 2; ++i)
#pragma unroll
            for (int n = 0; n < 8; ++n) acc2[i][n] = (f32x4){0.f, 0.f, 0.f, 0.f};
#pragma unroll
        for (int ks = 0; ks < 4; ++ks) {
            short8 h0 = *(const short8*)&Hm[32 * half + m][32 * ks + q * 8];
            short8 h1 = *(const short8*)&Hm[32 * half + 16 + m][32 * ks + q * 8];
#pragma unroll
            for (int n = 0; n < 8; ++n) {
                acc2[0][n] = __builtin_amdgcn_mfma_f32_16x16x32_bf16(h0, cb[ks][n], acc2[0][n], 0, 0, 0);
                acc2[1][n] = __builtin_amdgcn_mfma_f32_16x16x32_bf16(h1, cb[ks][n], acc2[1][n], 0, 0, 0);
            }
        }
#pragma unroll
        for (int i = 0; i < 2; ++i) {
            int rb = 32 * half + 16 * i + q * 4;
#pragma unroll
            for (int rr = 0; rr < 4; ++rr) {
                int rl = rb + rr;
                if (rl < rows) {
                    int en = s_ent[rl];
                    int tk = en & 0xFFFF, sl = en >> 16;
                    if (use_part) {
                        u16* pp = part + ((size_t)sl * NTOK + tk) * DM + 128 * wv + m;
#pragma unroll
                        for (int n = 0; n < 8; ++n) pp[16 * n] = f2bf(acc2[i][n][rr]);
                    } else {
                        float* op = out + (size_t)tk * DM + 128 * wv + m;
#pragma unroll
                        for (int n = 0; n < 8; ++n) atomicAdd(&op[16 * n], acc2[i][n][rr]);
                    }
                }
            }
        }
    }
}

// ---------------- combine: out[t][c] = sum_k part[k][t][c] ----------------
__global__ __launch_bounds__(256) void combine_kernel(const u16* __restrict__ part,
                                                      float* __restrict__ out) {
    size_t off = ((size_t)blockIdx.x * 256 + threadIdx.x) * 8;
    float s[8] = {0, 0, 0, 0, 0, 0, 0, 0};
#pragma unroll
    for (int k = 0; k < TK; ++k) {
        u16x8 p = *(const u16x8*)(part + (size_t)k * NTOK * DM + off);
#pragma unroll
        for (int j = 0; j < 8; ++j) s[j] += bf2f(p[j]);
    }
    *(f32x4*)(out + off)     = (f32x4){s[0], s[1], s[2], s[3]};
    *(f32x4*)(out + off + 4) = (f32x4){s[4], s[5], s[6], s[7]};
}

extern "C" void kernel_launch(void* const* d_in, const int* in_sizes, int n_in,
                              void* d_out, int out_size, void* d_ws, size_t ws_size,
                              hipStream_t stream) {
    const float* x   = (const float*)d_in[0];   // [N, D]
    const float* sel = (const float*)d_in[1];   // [E, D]
    const float* w1  = (const float*)d_in[2];   // [E, D, H]
    const float* w2  = (const float*)d_in[3];   // [E, H, D]
    float* out = (float*)d_out;                 // [N, D]

    char* ws = (char*)d_ws;
    int*   counts    = (int*)(ws);                                   // 256B
    int*   tok_list  = (int*)(ws + 2048);                            // 512KB (slot<<16 | tok)
    float* gate_list = (float*)(ws + 2048 + (size_t)NE * NTOK * 4);  // 512KB
    u16*   xbf  = (u16*)(ws + 2048 + (size_t)NE * NTOK * 8);         // 4MB
    u16*   wf1  = xbf + (size_t)NTOK * DM;                           // 4MB
    u16*   wf2  = wf1 + (size_t)NE * HD * DM;                        // 4MB
    u16*   part = wf2 + (size_t)NE * HD * DM;                        // 16.8MB (optional)

    size_t need = 2048 + (size_t)NE * NTOK * 8 + (size_t)NTOK * DM * 2
                + 2 * (size_t)NE * HD * DM * 2 + (size_t)TK * NTOK * DM * 2;
    int use_part = (ws_size >= need) ? 1 : 0;

    if (!use_part)
        hipMemsetAsync(d_out, 0, (size_t)NTOK * DM * sizeof(float), stream);

    swizzle_kernel<<<1024, 256, 0, stream>>>(w1, w2, wf1, wf2, counts);
    router_kernel<<<NTOK / 4, 256, 0, stream>>>(x, sel, counts, tok_list, gate_list, xbf);
    moe_mlp_kernel<<<288, 256, 0, stream>>>(xbf, wf1, wf2, counts, tok_list, gate_list,
                                            part, out, use_part);
    if (use_part)
        combine_kernel<<<NTOK * DM / 8 / 256, 256, 0, stream>>>(part, out);
}

// Round 7
// 162.399 us; speedup vs baseline: 1.0141x; 1.0141x over previous
//
#include <hip/hip_runtime.h>
#include <hip/hip_bf16.h>

// Problem constants: N tokens, D d_model, E experts, H hidden, K top-k
#define NTOK 4096
#define DM   512
#define NE   32
#define HD   128
#define TK   4

typedef unsigned short u16;
typedef unsigned int   u32;
typedef u16   u16x4 __attribute__((ext_vector_type(4)));
typedef u16   u16x8 __attribute__((ext_vector_type(8)));
typedef short short8 __attribute__((ext_vector_type(8)));
typedef float f32x4 __attribute__((ext_vector_type(4)));

__device__ __forceinline__ u16 f2bf(float f) {
    union { float f; u32 u; } v; v.f = f;
    return (u16)((v.u + 0x7FFFu + ((v.u >> 16) & 1u)) >> 16);   // RNE
}
__device__ __forceinline__ float bf2f(u16 h) {
    union { u32 u; float f; } v; v.u = ((u32)h) << 16; return v.f;
}

// ---------------- weight swizzle (no LDS -> high occupancy, deep ILP) ----------------
// fp32 [E][Kdim][Ndim] -> bf16 fragment-major:
//   frag[wl][lane][j] = in[e][32*ks + (lane>>4)*8 + j][16*nt + (lane&15)]
// W1: Kdim=512, Ndim=128, wl = e*128 + ks*8  + nt  (frags 0..4095)
// W2: Kdim=128, Ndim=512, wl = e*128 + ks*32 + nt  (frags 4096..8191)
__global__ __launch_bounds__(256) void swizzle_kernel(const float* __restrict__ w1,
                                                      const float* __restrict__ w2,
                                                      u16* __restrict__ wf1,
                                                      u16* __restrict__ wf2,
                                                      int* __restrict__ counts) {
    int tid = threadIdx.x;
    if (blockIdx.x == 0 && tid < NE) counts[tid] = 0;   // replaces memset dispatch
    int wv = tid >> 6, lane = tid & 63;
    int m = lane & 15, q = lane >> 4;
    int f0 = (blockIdx.x * 4 + wv) * 2;

    const float* in[2]; u16* outp[2]; int Nd[2];
#pragma unroll
    for (int u = 0; u < 2; ++u) {
        int w = f0 + u;
        if (w < 4096) {
            int e = w >> 7, rem = w & 127, ks = rem >> 3, nt = rem & 7;
            in[u] = w1 + (size_t)e * DM * HD + (size_t)(32 * ks + q * 8) * HD + 16 * nt + m;
            Nd[u] = HD;
            outp[u] = wf1 + (size_t)w * 512 + lane * 8;
        } else {
            int wl = w - 4096, e = wl >> 7, rem = wl & 127, ks = rem >> 5, nt = rem & 31;
            in[u] = w2 + (size_t)e * HD * DM + (size_t)(32 * ks + q * 8) * DM + 16 * nt + m;
            Nd[u] = DM;
            outp[u] = wf2 + (size_t)wl * 512 + lane * 8;
        }
    }
    float v[2][8];
#pragma unroll
    for (int u = 0; u < 2; ++u)
#pragma unroll
        for (int j = 0; j < 8; ++j) v[u][j] = in[u][(size_t)j * Nd[u]];
#pragma unroll
    for (int u = 0; u < 2; ++u) {
        u16x8 h;
#pragma unroll
        for (int j = 0; j < 8; ++j) h[j] = f2bf(v[u][j]);
        *(u16x8*)outp[u] = h;
    }
}

// ---------------- router: sel staged in LDS (no gathers), thread=(tok,seg,e) fp64 ----------------
__global__ __launch_bounds__(256) void router_kernel(const float* __restrict__ x,
                                                     const float* __restrict__ sel,
                                                     int* __restrict__ counts,
                                                     int* __restrict__ tok_list,
                                                     float* __restrict__ gate_list,
                                                     u16* __restrict__ xbf) {
    __shared__ float  sl[32][516];                  // stride 516: 8 e-rows/wave span all banks
    __shared__ float  xs[4][520];                   // stride 520: 4 tok quads, 2-way max
    __shared__ double sc[4][33];
    int tid = threadIdx.x;
    int tb = blockIdx.x * 4;

    // stage sel (32 x 512 fp32, 64 KB) -> LDS, fully coalesced
#pragma unroll
    for (int rep = 0; rep < 16; ++rep) {
        int idx = (rep * 256 + tid) * 4;            // element in 32x512
        int row = idx >> 9, col = idx & 511;
        *(f32x4*)&sl[row][col] = *(const f32x4*)(sel + idx);
    }
    // stage x (4 x 512) -> LDS fp32, write xbf bf16 on the way
#pragma unroll
    for (int rep = 0; rep < 2; ++rep) {
        int idx = (rep * 256 + tid) * 4;            // element in 4x512 tile
        int row = idx >> 9, col = idx & 511;
        f32x4 v = *(const f32x4*)(x + (size_t)(tb + row) * DM + col);
        *(f32x4*)&xs[row][col] = v;
        u16x4 h;
#pragma unroll
        for (int j = 0; j < 4; ++j) h[j] = f2bf(v[j]);
        *(u16x4*)(xbf + (size_t)(tb + row) * DM + col) = h;
    }
    __syncthreads();

    // thread: tok = tid&3, seg = (tid>>2)&1, e = tid>>3 ; 256-long fp64 dot, 4 chains
    int tok = tid & 3, seg = (tid >> 2) & 1, e = tid >> 3;
    const float* sp = &sl[e][seg * 256];
    const float* xp = &xs[tok][seg * 256];
    double pa = 0.0, pb = 0.0, pc = 0.0, pd = 0.0;
#pragma unroll 4
    for (int j = 0; j < 256; j += 16) {
        f32x4 x0 = *(const f32x4*)(xp + j);
        f32x4 x1 = *(const f32x4*)(xp + j + 4);
        f32x4 x2 = *(const f32x4*)(xp + j + 8);
        f32x4 x3 = *(const f32x4*)(xp + j + 12);
        f32x4 s0 = *(const f32x4*)(sp + j);
        f32x4 s1 = *(const f32x4*)(sp + j + 4);
        f32x4 s2 = *(const f32x4*)(sp + j + 8);
        f32x4 s3 = *(const f32x4*)(sp + j + 12);
#pragma unroll
        for (int k = 0; k < 4; ++k) {
            pa = fma((double)x0[k], (double)s0[k], pa);
            pb = fma((double)x1[k], (double)s1[k], pb);
            pc = fma((double)x2[k], (double)s2[k], pc);
            pd = fma((double)x3[k], (double)s3[k], pd);
        }
    }
    double p = (pa + pb) + (pc + pd);
    p += __shfl_xor(p, 4);                          // combine the two K-halves (bit2 of tid)
    if (seg == 0) sc[tok][e] = p;
    __syncthreads();

    if (tid < 4) {
        int t = tb + tid;
        unsigned mask = 0;
        for (int k = 0; k < TK; ++k) {
            double best = -1e300; int be = 0;
            for (int ee = 0; ee < NE; ++ee) {
                double v = sc[tid][ee];
                if (!((mask >> ee) & 1u) && v > best) { best = v; be = ee; }
            }
            mask |= 1u << be;
            float gate = 1.0f / (1.0f + __expf(-(float)best));
            int pos = atomicAdd(&counts[be], 1);
            tok_list[(size_t)be * NTOK + pos]  = (k << 16) | t;   // slot in high bits
            gate_list[(size_t)be * NTOK + pos] = gate;
        }
    }
}

// ---------------- fused expert MLP ----------------
// per (expert, 64-token tile); GEMM1 waves split 2x2 (rows x cols), paired-k double
// buffer; GEMM2 each wave owns a distinct 128-col group, all B up-front.
__global__ __launch_bounds__(256, 2) void moe_mlp_kernel(const u16* __restrict__ xbf,
                                                         const u16* __restrict__ wf1,
                                                         const u16* __restrict__ wf2,
                                                         const int* __restrict__ counts,
                                                         const int* __restrict__ tok_list,
                                                         const float* __restrict__ gate_list,
                                                         u16* __restrict__ part,
                                                         float* __restrict__ out,
                                                         int use_part) {
    __shared__ int   s_cnt[NE];
    __shared__ int   s_ent[64];
    __shared__ float s_gate[64];
    __shared__ __align__(16) u16 Hm[64][136];       // 272B stride: 16B-aligned, ~2-way banks

    int tid = threadIdx.x;
    if (tid < NE) s_cnt[tid] = counts[tid];         // one coalesced load, not 32 serial
    __syncthreads();

    int b = blockIdx.x;
    int e = -1, t = 0, rows = 0, pre = 0;
#pragma unroll 8
    for (int ee = 0; ee < NE; ++ee) {
        int cc = s_cnt[ee];
        int nt = (cc + 63) >> 6;
        if (e < 0 && b < pre + nt) { e = ee; t = b - pre; rows = cc - t * 64; if (rows > 64) rows = 64; }
        pre += nt;
    }
    if (e < 0) return;

    if (tid < 64) {
        int base = e * NTOK + t * 64;
        bool val = tid < rows;
        s_ent[tid]  = tok_list[base + (val ? tid : 0)];
        s_gate[tid] = val ? gate_list[base + tid] : 0.0f;
    }
    __syncthreads();

    int wv = tid >> 6, lane = tid & 63, m = lane & 15, q = lane >> 4;
    int r = wv >> 1, c = wv & 1;                    // GEMM1: rows 32r..+32, cols 64c..+64
    const u16* w1f = wf1 + (size_t)e * (128 * 512);
    const u16* w2f = wf2 + (size_t)e * (128 * 512);

    const u16* a0 = xbf + (size_t)(s_ent[32 * r + m] & 0xFFFF) * DM + q * 8;
    const u16* a1 = xbf + (size_t)(s_ent[32 * r + 16 + m] & 0xFFFF) * DM + q * 8;

    // GEMM1: k-steps in pairs, double-buffered (12 loads in flight)
    short8 ab[2][2][2];                             // [buf][kk][mtile]
    short8 bb[2][2][4];                             // [buf][kk][ntile]
#pragma unroll
    for (int kk = 0; kk < 2; ++kk) {
        ab[0][kk][0] = *(const short8*)(a0 + 32 * kk);
        ab[0][kk][1] = *(const short8*)(a1 + 32 * kk);
        const u16* bp = w1f + (size_t)kk * 4096 + (size_t)(4 * c) * 512 + lane * 8;
#pragma unroll
        for (int n = 0; n < 4; ++n) bb[0][kk][n] = *(const short8*)(bp + n * 512);
    }
    f32x4 acc[2][4];
#pragma unroll
    for (int i = 0; i < 2; ++i)
#pragma unroll
        for (int n = 0; n < 4; ++n) acc[i][n] = (f32x4){0.f, 0.f, 0.f, 0.f};

#pragma unroll
    for (int kp = 0; kp < 8; ++kp) {
        int cur = kp & 1, nxt = cur ^ 1;
        if (kp < 7) {
            int ks0 = 2 * (kp + 1);
#pragma unroll
            for (int kk = 0; kk < 2; ++kk) {
                ab[nxt][kk][0] = *(const short8*)(a0 + 32 * (ks0 + kk));
                ab[nxt][kk][1] = *(const short8*)(a1 + 32 * (ks0 + kk));
                const u16* bp = w1f + (size_t)(ks0 + kk) * 4096 + (size_t)(4 * c) * 512 + lane * 8;
#pragma unroll
                for (int n = 0; n < 4; ++n) bb[nxt][kk][n] = *(const short8*)(bp + n * 512);
            }
        }
#pragma unroll
        for (int kk = 0; kk < 2; ++kk)
#pragma unroll
            for (int i = 0; i < 2; ++i)
#pragma unroll
                for (int n = 0; n < 4; ++n)
                    acc[i][n] = __builtin_amdgcn_mfma_f32_16x16x32_bf16(ab[cur][kk][i],
                                                                        bb[cur][kk][n],
                                                                        acc[i][n], 0, 0, 0);
    }

    // relu * gate -> Hm
#pragma unroll
    for (int i = 0; i < 2; ++i) {
        int rb = 32 * r + 16 * i + q * 4;
#pragma unroll
        for (int n = 0; n < 4; ++n)
#pragma unroll
            for (int rr = 0; rr < 4; ++rr)
                Hm[rb + rr][64 * c + 16 * n + m] =
                    f2bf(fmaxf(acc[i][n][rr], 0.f) * s_gate[rb + rr]);
    }

    // GEMM2: wave owns cols [128*wv, 128*wv+128); all 32 B-frags issued before barrier
    short8 cb[4][8];
#pragma unroll
    for (int ks = 0; ks < 4; ++ks) {
        const u16* bp = w2f + (size_t)(ks * 32 + wv * 8) * 512 + lane * 8;
#pragma unroll
        for (int n = 0; n < 8; ++n) cb[ks][n] = *(const short8*)(bp + n * 512);
    }
    __syncthreads();                                // Hm ready

#pragma unroll
    for (int half = 0; half < 2; ++half) {
        f32x4 acc2[2][8];
#pragma unroll
        for (int i = 0; i < 2; ++i)
#pragma unroll
            for (int n = 0; n < 8; ++n) acc2[i][n] = (f32x4){0.f, 0.f, 0.f, 0.f};
#pragma unroll
        for (int ks = 0; ks < 4; ++ks) {
            short8 h0 = *(const short8*)&Hm[32 * half + m][32 * ks + q * 8];
            short8 h1 = *(const short8*)&Hm[32 * half + 16 + m][32 * ks + q * 8];
#pragma unroll
            for (int n = 0; n < 8; ++n) {
                acc2[0][n] = __builtin_amdgcn_mfma_f32_16x16x32_bf16(h0, cb[ks][n], acc2[0][n], 0, 0, 0);
                acc2[1][n] = __builtin_amdgcn_mfma_f32_16x16x32_bf16(h1, cb[ks][n], acc2[1][n], 0, 0, 0);
            }
        }
#pragma unroll
        for (int i = 0; i < 2; ++i) {
            int rb = 32 * half + 16 * i + q * 4;
#pragma unroll
            for (int rr = 0; rr < 4; ++rr) {
                int rl = rb + rr;
                if (rl < rows) {
                    int en = s_ent[rl];
                    int tk = en & 0xFFFF, sl = en >> 16;
                    if (use_part) {
                        u16* pp = part + ((size_t)sl * NTOK + tk) * DM + 128 * wv + m;
#pragma unroll
                        for (int n = 0; n < 8; ++n) pp[16 * n] = f2bf(acc2[i][n][rr]);
                    } else {
                        float* op = out + (size_t)tk * DM + 128 * wv + m;
#pragma unroll
                        for (int n = 0; n < 8; ++n) atomicAdd(&op[16 * n], acc2[i][n][rr]);
                    }
                }
            }
        }
    }
}

// ---------------- combine: out[t][c] = sum_k part[k][t][c] ----------------
__global__ __launch_bounds__(256) void combine_kernel(const u16* __restrict__ part,
                                                      float* __restrict__ out) {
    size_t off = ((size_t)blockIdx.x * 256 + threadIdx.x) * 8;
    float s[8] = {0, 0, 0, 0, 0, 0, 0, 0};
#pragma unroll
    for (int k = 0; k < TK; ++k) {
        u16x8 p = *(const u16x8*)(part + (size_t)k * NTOK * DM + off);
#pragma unroll
        for (int j = 0; j < 8; ++j) s[j] += bf2f(p[j]);
    }
    *(f32x4*)(out + off)     = (f32x4){s[0], s[1], s[2], s[3]};
    *(f32x4*)(out + off + 4) = (f32x4){s[4], s[5], s[6], s[7]};
}

extern "C" void kernel_launch(void* const* d_in, const int* in_sizes, int n_in,
                              void* d_out, int out_size, void* d_ws, size_t ws_size,
                              hipStream_t stream) {
    const float* x   = (const float*)d_in[0];   // [N, D]
    const float* sel = (const float*)d_in[1];   // [E, D]
    const float* w1  = (const float*)d_in[2];   // [E, D, H]
    const float* w2  = (const float*)d_in[3];   // [E, H, D]
    float* out = (float*)d_out;                 // [N, D]

    char* ws = (char*)d_ws;
    int*   counts    = (int*)(ws);                                   // 256B
    int*   tok_list  = (int*)(ws + 2048);                            // 512KB (slot<<16 | tok)
    float* gate_list = (float*)(ws + 2048 + (size_t)NE * NTOK * 4);  // 512KB
    u16*   xbf  = (u16*)(ws + 2048 + (size_t)NE * NTOK * 8);         // 4MB
    u16*   wf1  = xbf + (size_t)NTOK * DM;                           // 4MB
    u16*   wf2  = wf1 + (size_t)NE * HD * DM;                        // 4MB
    u16*   part = wf2 + (size_t)NE * HD * DM;                        // 16.8MB (optional)

    size_t need = 2048 + (size_t)NE * NTOK * 8 + (size_t)NTOK * DM * 2
                + 2 * (size_t)NE * HD * DM * 2 + (size_t)TK * NTOK * DM * 2;
    int use_part = (ws_size >= need) ? 1 : 0;

    if (!use_part)
        hipMemsetAsync(d_out, 0, (size_t)NTOK * DM * sizeof(float), stream);

    swizzle_kernel<<<1024, 256, 0, stream>>>(w1, w2, wf1, wf2, counts);
    router_kernel<<<NTOK / 4, 256, 0, stream>>>(x, sel, counts, tok_list, gate_list, xbf);
    moe_mlp_kernel<<<288, 256, 0, stream>>>(xbf, wf1, wf2, counts, tok_list, gate_list,
                                            part, out, use_part);
    if (use_part)
        combine_kernel<<<NTOK * DM / 8 / 256, 256, 0, stream>>>(part, out);
}

// Round 8
// 136.802 us; speedup vs baseline: 1.2038x; 1.1871x over previous
//
#include <hip/hip_runtime.h>
#include <hip/hip_bf16.h>

// Problem constants: N tokens, D d_model, E experts, H hidden, K top-k
#define NTOK 4096
#define DM   512
#define NE   32
#define HD   128
#define TK   4

typedef unsigned short u16;
typedef unsigned int   u32;
typedef u16   u16x4 __attribute__((ext_vector_type(4)));
typedef u16   u16x8 __attribute__((ext_vector_type(8)));
typedef short short8 __attribute__((ext_vector_type(8)));
typedef float f32x4 __attribute__((ext_vector_type(4)));

__device__ __forceinline__ u16 f2bf(float f) {
    union { float f; u32 u; } v; v.f = f;
    return (u16)((v.u + 0x7FFFu + ((v.u >> 16) & 1u)) >> 16);   // RNE
}
__device__ __forceinline__ float bf2f(u16 h) {
    union { u32 u; float f; } v; v.u = ((u32)h) << 16; return v.f;
}

// ---------------- weight swizzle (no LDS -> high occupancy, deep ILP) ----------------
// fp32 [E][Kdim][Ndim] -> bf16 fragment-major:
//   frag[wl][lane][j] = in[e][32*ks + (lane>>4)*8 + j][16*nt + (lane&15)]
// W1: Kdim=512, Ndim=128, wl = e*128 + ks*8  + nt  (frags 0..4095)
// W2: Kdim=128, Ndim=512, wl = e*128 + ks*32 + nt  (frags 4096..8191)
__global__ __launch_bounds__(256) void swizzle_kernel(const float* __restrict__ w1,
                                                      const float* __restrict__ w2,
                                                      u16* __restrict__ wf1,
                                                      u16* __restrict__ wf2) {
    int tid = threadIdx.x;
    int wv = tid >> 6, lane = tid & 63;
    int m = lane & 15, q = lane >> 4;
    int f0 = (blockIdx.x * 4 + wv) * 2;

    const float* in[2]; u16* outp[2]; int Nd[2];
#pragma unroll
    for (int u = 0; u < 2; ++u) {
        int w = f0 + u;
        if (w < 4096) {
            int e = w >> 7, rem = w & 127, ks = rem >> 3, nt = rem & 7;
            in[u] = w1 + (size_t)e * DM * HD + (size_t)(32 * ks + q * 8) * HD + 16 * nt + m;
            Nd[u] = HD;
            outp[u] = wf1 + (size_t)w * 512 + lane * 8;
        } else {
            int wl = w - 4096, e = wl >> 7, rem = wl & 127, ks = rem >> 5, nt = rem & 31;
            in[u] = w2 + (size_t)e * HD * DM + (size_t)(32 * ks + q * 8) * DM + 16 * nt + m;
            Nd[u] = DM;
            outp[u] = wf2 + (size_t)wl * 512 + lane * 8;
        }
    }
    float v[2][8];
#pragma unroll
    for (int u = 0; u < 2; ++u)
#pragma unroll
        for (int j = 0; j < 8; ++j) v[u][j] = in[u][(size_t)j * Nd[u]];
#pragma unroll
    for (int u = 0; u < 2; ++u) {
        u16x8 h;
#pragma unroll
        for (int j = 0; j < 8; ++j) h[j] = f2bf(v[u][j]);
        *(u16x8*)outp[u] = h;
    }
}

// ---------------- router: NO global atomics; writes dense per-token route ----------------
__global__ __launch_bounds__(256) void router_kernel(const float* __restrict__ x,
                                                     const float* __restrict__ sel,
                                                     u32* __restrict__ route_e,
                                                     float* __restrict__ route_g,
                                                     u16* __restrict__ xbf) {
    __shared__ float  sl[32][516];
    __shared__ float  xs[4][520];
    __shared__ double sc[4][33];
    int tid = threadIdx.x;
    int tb = blockIdx.x * 4;

    // stage sel (32 x 512 fp32, 64 KB) -> LDS, fully coalesced
#pragma unroll
    for (int rep = 0; rep < 16; ++rep) {
        int idx = (rep * 256 + tid) * 4;            // element in 32x512
        int row = idx >> 9, col = idx & 511;
        *(f32x4*)&sl[row][col] = *(const f32x4*)(sel + idx);
    }
    // stage x (4 x 512) -> LDS fp32, write xbf bf16 on the way
#pragma unroll
    for (int rep = 0; rep < 2; ++rep) {
        int idx = (rep * 256 + tid) * 4;            // element in 4x512 tile
        int row = idx >> 9, col = idx & 511;
        f32x4 v = *(const f32x4*)(x + (size_t)(tb + row) * DM + col);
        *(f32x4*)&xs[row][col] = v;
        u16x4 h;
#pragma unroll
        for (int j = 0; j < 4; ++j) h[j] = f2bf(v[j]);
        *(u16x4*)(xbf + (size_t)(tb + row) * DM + col) = h;
    }
    __syncthreads();

    // thread: tok = tid&3, seg = (tid>>2)&1, e = tid>>3 ; 256-long fp64 dot, 4 chains
    int tok = tid & 3, seg = (tid >> 2) & 1, e = tid >> 3;
    const float* sp = &sl[e][seg * 256];
    const float* xp = &xs[tok][seg * 256];
    double pa = 0.0, pb = 0.0, pc = 0.0, pd = 0.0;
#pragma unroll 4
    for (int j = 0; j < 256; j += 16) {
        f32x4 x0 = *(const f32x4*)(xp + j);
        f32x4 x1 = *(const f32x4*)(xp + j + 4);
        f32x4 x2 = *(const f32x4*)(xp + j + 8);
        f32x4 x3 = *(const f32x4*)(xp + j + 12);
        f32x4 s0 = *(const f32x4*)(sp + j);
        f32x4 s1 = *(const f32x4*)(sp + j + 4);
        f32x4 s2 = *(const f32x4*)(sp + j + 8);
        f32x4 s3 = *(const f32x4*)(sp + j + 12);
#pragma unroll
        for (int k = 0; k < 4; ++k) {
            pa = fma((double)x0[k], (double)s0[k], pa);
            pb = fma((double)x1[k], (double)s1[k], pb);
            pc = fma((double)x2[k], (double)s2[k], pc);
            pd = fma((double)x3[k], (double)s3[k], pd);
        }
    }
    double p = (pa + pb) + (pc + pd);
    p += __shfl_xor(p, 4);                          // combine the two K-halves (bit2 of tid)
    if (seg == 0) sc[tok][e] = p;
    __syncthreads();

    if (tid < 4) {
        int t = tb + tid;
        unsigned mask = 0;
        u32 eids = 0;
        f32x4 gs;
        for (int k = 0; k < TK; ++k) {
            double best = -1e300; int be = 0;
            for (int ee = 0; ee < NE; ++ee) {
                double v = sc[tid][ee];
                if (!((mask >> ee) & 1u) && v > best) { best = v; be = ee; }
            }
            mask |= 1u << be;
            eids |= (u32)be << (8 * k);
            gs[k] = 1.0f / (1.0f + __expf(-(float)best));
        }
        route_e[t] = eids;
        *(f32x4*)&route_g[4 * t] = gs;
    }
}

// ---------------- build lists: 1 block per expert, LDS counter only ----------------
__global__ __launch_bounds__(256) void build_kernel(const u32* __restrict__ route_e,
                                                    const float* __restrict__ route_g,
                                                    int* __restrict__ counts,
                                                    int* __restrict__ tok_list,
                                                    float* __restrict__ gate_list) {
    int e = blockIdx.x;
    __shared__ int cnt;
    if (threadIdx.x == 0) cnt = 0;
    __syncthreads();
#pragma unroll
    for (int rep = 0; rep < NTOK / 256; ++rep) {
        int t = rep * 256 + threadIdx.x;            // coalesced u32 load
        u32 eid = route_e[t];
        int k = -1;
        if ((eid & 255u) == (u32)e) k = 0;
        else if (((eid >> 8) & 255u) == (u32)e) k = 1;
        else if (((eid >> 16) & 255u) == (u32)e) k = 2;
        else if (((eid >> 24) & 255u) == (u32)e) k = 3;
        if (k >= 0) {
            int pos = atomicAdd(&cnt, 1);           // LDS atomic: block-local, cheap
            tok_list[e * NTOK + pos]  = (k << 16) | t;
            gate_list[e * NTOK + pos] = route_g[4 * t + k];
        }
    }
    __syncthreads();
    if (threadIdx.x == 0) counts[e] = cnt;
}

// ---------------- fused expert MLP ----------------
// per (expert, 64-token tile); GEMM1 waves split 2x2 (rows x cols), paired-k double
// buffer; GEMM2 each wave owns a distinct 128-col group, all B up-front.
__global__ __launch_bounds__(256, 2) void moe_mlp_kernel(const u16* __restrict__ xbf,
                                                         const u16* __restrict__ wf1,
                                                         const u16* __restrict__ wf2,
                                                         const int* __restrict__ counts,
                                                         const int* __restrict__ tok_list,
                                                         const float* __restrict__ gate_list,
                                                         u16* __restrict__ part,
                                                         float* __restrict__ out,
                                                         int use_part) {
    __shared__ int   s_cnt[NE];
    __shared__ int   s_ent[64];
    __shared__ float s_gate[64];
    __shared__ __align__(16) u16 Hm[64][136];       // 272B stride: 16B-aligned, ~2-way banks

    int tid = threadIdx.x;
    if (tid < NE) s_cnt[tid] = counts[tid];         // one coalesced load, not 32 serial
    __syncthreads();

    int b = blockIdx.x;
    int e = -1, t = 0, rows = 0, pre = 0;
#pragma unroll 8
    for (int ee = 0; ee < NE; ++ee) {
        int cc = s_cnt[ee];
        int nt = (cc + 63) >> 6;
        if (e < 0 && b < pre + nt) { e = ee; t = b - pre; rows = cc - t * 64; if (rows > 64) rows = 64; }
        pre += nt;
    }
    if (e < 0) return;

    if (tid < 64) {
        int base = e * NTOK + t * 64;
        bool val = tid < rows;
        s_ent[tid]  = tok_list[base + (val ? tid : 0)];
        s_gate[tid] = val ? gate_list[base + tid] : 0.0f;
    }
    __syncthreads();

    int wv = tid >> 6, lane = tid & 63, m = lane & 15, q = lane >> 4;
    int r = wv >> 1, c = wv & 1;                    // GEMM1: rows 32r..+32, cols 64c..+64
    const u16* w1f = wf1 + (size_t)e * (128 * 512);
    const u16* w2f = wf2 + (size_t)e * (128 * 512);

    const u16* a0 = xbf + (size_t)(s_ent[32 * r + m] & 0xFFFF) * DM + q * 8;
    const u16* a1 = xbf + (size_t)(s_ent[32 * r + 16 + m] & 0xFFFF) * DM + q * 8;

    // GEMM1: k-steps in pairs, double-buffered (12 loads in flight)
    short8 ab[2][2][2];                             // [buf][kk][mtile]
    short8 bb[2][2][4];                             // [buf][kk][ntile]
#pragma unroll
    for (int kk = 0; kk < 2; ++kk) {
        ab[0][kk][0] = *(const short8*)(a0 + 32 * kk);
        ab[0][kk][1] = *(const short8*)(a1 + 32 * kk);
        const u16* bp = w1f + (size_t)kk * 4096 + (size_t)(4 * c) * 512 + lane * 8;
#pragma unroll
        for (int n = 0; n < 4; ++n) bb[0][kk][n] = *(const short8*)(bp + n * 512);
    }
    f32x4 acc[2][4];
#pragma unroll
    for (int i = 0; i < 2; ++i)
#pragma unroll
        for (int n = 0; n < 4; ++n) acc[i][n] = (f32x4){0.f, 0.f, 0.f, 0.f};

#pragma unroll
    for (int kp = 0; kp < 8; ++kp) {
        int cur = kp & 1, nxt = cur ^ 1;
        if (kp < 7) {
            int ks0 = 2 * (kp + 1);
#pragma unroll
            for (int kk = 0; kk < 2; ++kk) {
                ab[nxt][kk][0] = *(const short8*)(a0 + 32 * (ks0 + kk));
                ab[nxt][kk][1] = *(const short8*)(a1 + 32 * (ks0 + kk));
                const u16* bp = w1f + (size_t)(ks0 + kk) * 4096 + (size_t)(4 * c) * 512 + lane * 8;
#pragma unroll
                for (int n = 0; n < 4; ++n) bb[nxt][kk][n] = *(const short8*)(bp + n * 512);
            }
        }
#pragma unroll
        for (int kk = 0; kk < 2; ++kk)
#pragma unroll
            for (int i = 0; i < 2; ++i)
#pragma unroll
                for (int n = 0; n < 4; ++n)
                    acc[i][n] = __builtin_amdgcn_mfma_f32_16x16x32_bf16(ab[cur][kk][i],
                                                                        bb[cur][kk][n],
                                                                        acc[i][n], 0, 0, 0);
    }

    // relu * gate -> Hm
#pragma unroll
    for (int i = 0; i < 2; ++i) {
        int rb = 32 * r + 16 * i + q * 4;
#pragma unroll
        for (int n = 0; n < 4; ++n)
#pragma unroll
            for (int rr = 0; rr < 4; ++rr)
                Hm[rb + rr][64 * c + 16 * n + m] =
                    f2bf(fmaxf(acc[i][n][rr], 0.f) * s_gate[rb + rr]);
    }

    // GEMM2: wave owns cols [128*wv, 128*wv+128); all 32 B-frags issued before barrier
    short8 cb[4][8];
#pragma unroll
    for (int ks = 0; ks < 4; ++ks) {
        const u16* bp = w2f + (size_t)(ks * 32 + wv * 8) * 512 + lane * 8;
#pragma unroll
        for (int n = 0; n < 8; ++n) cb[ks][n] = *(const short8*)(bp + n * 512);
    }
    __syncthreads();                                // Hm ready

#pragma unroll
    for (int half = 0; half < 2; ++half) {
        f32x4 acc2[2][8];
#pragma unroll
        for (int i = 0; i < 2; ++i)
#pragma unroll
            for (int n = 0; n < 8; ++n) acc2[i][n] = (f32x4){0.f, 0.f, 0.f, 0.f};
#pragma unroll
        for (int ks = 0; ks < 4; ++ks) {
            short8 h0 = *(const short8*)&Hm[32 * half + m][32 * ks + q * 8];
            short8 h1 = *(const short8*)&Hm[32 * half + 16 + m][32 * ks + q * 8];
#pragma unroll
            for (int n = 0; n < 8; ++n) {
                acc2[0][n] = __builtin_amdgcn_mfma_f32_16x16x32_bf16(h0, cb[ks][n], acc2[0][n], 0, 0, 0);
                acc2[1][n] = __builtin_amdgcn_mfma_f32_16x16x32_bf16(h1, cb[ks][n], acc2[1][n], 0, 0, 0);
            }
        }
#pragma unroll
        for (int i = 0; i < 2; ++i) {
            int rb = 32 * half + 16 * i + q * 4;
#pragma unroll
            for (int rr = 0; rr < 4; ++rr) {
                int rl = rb + rr;
                if (rl < rows) {
                    int en = s_ent[rl];
                    int tk = en & 0xFFFF, sl = en >> 16;
                    if (use_part) {
                        u16* pp = part + ((size_t)sl * NTOK + tk) * DM + 128 * wv + m;
#pragma unroll
                        for (int n = 0; n < 8; ++n) pp[16 * n] = f2bf(acc2[i][n][rr]);
                    } else {
                        float* op = out + (size_t)tk * DM + 128 * wv + m;
#pragma unroll
                        for (int n = 0; n < 8; ++n) atomicAdd(&op[16 * n], acc2[i][n][rr]);
                    }
                }
            }
        }
    }
}

// ---------------- combine: out[t][c] = sum_k part[k][t][c] ----------------
__global__ __launch_bounds__(256) void combine_kernel(const u16* __restrict__ part,
                                                      float* __restrict__ out) {
    size_t off = ((size_t)blockIdx.x * 256 + threadIdx.x) * 8;
    float s[8] = {0, 0, 0, 0, 0, 0, 0, 0};
#pragma unroll
    for (int k = 0; k < TK; ++k) {
        u16x8 p = *(const u16x8*)(part + (size_t)k * NTOK * DM + off);
#pragma unroll
        for (int j = 0; j < 8; ++j) s[j] += bf2f(p[j]);
    }
    *(f32x4*)(out + off)     = (f32x4){s[0], s[1], s[2], s[3]};
    *(f32x4*)(out + off + 4) = (f32x4){s[4], s[5], s[6], s[7]};
}

extern "C" void kernel_launch(void* const* d_in, const int* in_sizes, int n_in,
                              void* d_out, int out_size, void* d_ws, size_t ws_size,
                              hipStream_t stream) {
    const float* x   = (const float*)d_in[0];   // [N, D]
    const float* sel = (const float*)d_in[1];   // [E, D]
    const float* w1  = (const float*)d_in[2];   // [E, D, H]
    const float* w2  = (const float*)d_in[3];   // [E, H, D]
    float* out = (float*)d_out;                 // [N, D]

    char* ws = (char*)d_ws;
    int*   counts    = (int*)(ws);                                   // 256 B
    u32*   route_e   = (u32*)(ws + 256);                             // 16 KB
    float* route_g   = (float*)(ws + 256 + (size_t)NTOK * 4);        // 64 KB
    char*  ws2       = ws + 256 + (size_t)NTOK * 20;
    int*   tok_list  = (int*)(ws2);                                  // 512 KB
    float* gate_list = (float*)(ws2 + (size_t)NE * NTOK * 4);        // 512 KB
    u16*   xbf  = (u16*)(ws2 + (size_t)NE * NTOK * 8);               // 4 MB
    u16*   wf1  = xbf + (size_t)NTOK * DM;                           // 4 MB
    u16*   wf2  = wf1 + (size_t)NE * HD * DM;                        // 4 MB
    u16*   part = wf2 + (size_t)NE * HD * DM;                        // 16.8 MB (optional)

    size_t need = 256 + (size_t)NTOK * 20 + (size_t)NE * NTOK * 8
                + (size_t)NTOK * DM * 2 + 2 * (size_t)NE * HD * DM * 2
                + (size_t)TK * NTOK * DM * 2;
    int use_part = (ws_size >= need) ? 1 : 0;

    if (!use_part)
        hipMemsetAsync(d_out, 0, (size_t)NTOK * DM * sizeof(float), stream);

    swizzle_kernel<<<1024, 256, 0, stream>>>(w1, w2, wf1, wf2);
    router_kernel<<<NTOK / 4, 256, 0, stream>>>(x, sel, route_e, route_g, xbf);
    build_kernel<<<NE, 256, 0, stream>>>(route_e, route_g, counts, tok_list, gate_list);
    moe_mlp_kernel<<<288, 256, 0, stream>>>(xbf, wf1, wf2, counts, tok_list, gate_list,
                                            part, out, use_part);
    if (use_part)
        combine_kernel<<<NTOK * DM / 8 / 256, 256, 0, stream>>>(part, out);
}

// Round 9
// 133.096 us; speedup vs baseline: 1.2374x; 1.0278x over previous
//
#include <hip/hip_runtime.h>
#include <hip/hip_bf16.h>

// Problem constants: N tokens, D d_model, E experts, H hidden, K top-k
#define NTOK 4096
#define DM   512
#define NE   32
#define HD   128
#define TK   4

typedef unsigned short u16;
typedef unsigned int   u32;
typedef u16   u16x4 __attribute__((ext_vector_type(4)));
typedef u16   u16x8 __attribute__((ext_vector_type(8)));
typedef short short8 __attribute__((ext_vector_type(8)));
typedef float f32x4 __attribute__((ext_vector_type(4)));

__device__ __forceinline__ u16 f2bf(float f) {
    union { float f; u32 u; } v; v.f = f;
    return (u16)((v.u + 0x7FFFu + ((v.u >> 16) & 1u)) >> 16);   // RNE
}
__device__ __forceinline__ float bf2f(u16 h) {
    union { u32 u; float f; } v; v.u = ((u32)h) << 16; return v.f;
}

// ---------------- weight swizzle (no LDS -> high occupancy, deep ILP) ----------------
// fp32 [E][Kdim][Ndim] -> bf16 fragment-major:
//   frag[wl][lane][j] = in[e][32*ks + (lane>>4)*8 + j][16*nt + (lane&15)]
__global__ __launch_bounds__(256) void swizzle_kernel(const float* __restrict__ w1,
                                                      const float* __restrict__ w2,
                                                      u16* __restrict__ wf1,
                                                      u16* __restrict__ wf2) {
    int tid = threadIdx.x;
    int wv = tid >> 6, lane = tid & 63;
    int m = lane & 15, q = lane >> 4;
    int f0 = (blockIdx.x * 4 + wv) * 2;

    const float* in[2]; u16* outp[2]; int Nd[2];
#pragma unroll
    for (int u = 0; u < 2; ++u) {
        int w = f0 + u;
        if (w < 4096) {
            int e = w >> 7, rem = w & 127, ks = rem >> 3, nt = rem & 7;
            in[u] = w1 + (size_t)e * DM * HD + (size_t)(32 * ks + q * 8) * HD + 16 * nt + m;
            Nd[u] = HD;
            outp[u] = wf1 + (size_t)w * 512 + lane * 8;
        } else {
            int wl = w - 4096, e = wl >> 7, rem = wl & 127, ks = rem >> 5, nt = rem & 31;
            in[u] = w2 + (size_t)e * HD * DM + (size_t)(32 * ks + q * 8) * DM + 16 * nt + m;
            Nd[u] = DM;
            outp[u] = wf2 + (size_t)wl * 512 + lane * 8;
        }
    }
    float v[2][8];
#pragma unroll
    for (int u = 0; u < 2; ++u)
#pragma unroll
        for (int j = 0; j < 8; ++j) v[u][j] = in[u][(size_t)j * Nd[u]];
#pragma unroll
    for (int u = 0; u < 2; ++u) {
        u16x8 h;
#pragma unroll
        for (int j = 0; j < 8; ++j) h[j] = f2bf(v[u][j]);
        *(u16x8*)outp[u] = h;
    }
}

// ---------------- router: NO global atomics; writes dense per-token route ----------------
__global__ __launch_bounds__(256) void router_kernel(const float* __restrict__ x,
                                                     const float* __restrict__ sel,
                                                     u32* __restrict__ route_e,
                                                     float* __restrict__ route_g,
                                                     u16* __restrict__ xbf) {
    __shared__ float  sl[32][516];
    __shared__ float  xs[4][520];
    __shared__ double sc[4][33];
    int tid = threadIdx.x;
    int tb = blockIdx.x * 4;

#pragma unroll
    for (int rep = 0; rep < 16; ++rep) {
        int idx = (rep * 256 + tid) * 4;            // element in 32x512
        int row = idx >> 9, col = idx & 511;
        *(f32x4*)&sl[row][col] = *(const f32x4*)(sel + idx);
    }
#pragma unroll
    for (int rep = 0; rep < 2; ++rep) {
        int idx = (rep * 256 + tid) * 4;            // element in 4x512 tile
        int row = idx >> 9, col = idx & 511;
        f32x4 v = *(const f32x4*)(x + (size_t)(tb + row) * DM + col);
        *(f32x4*)&xs[row][col] = v;
        u16x4 h;
#pragma unroll
        for (int j = 0; j < 4; ++j) h[j] = f2bf(v[j]);
        *(u16x4*)(xbf + (size_t)(tb + row) * DM + col) = h;
    }
    __syncthreads();

    int tok = tid & 3, seg = (tid >> 2) & 1, e = tid >> 3;
    const float* sp = &sl[e][seg * 256];
    const float* xp = &xs[tok][seg * 256];
    double pa = 0.0, pb = 0.0, pc = 0.0, pd = 0.0;
#pragma unroll 4
    for (int j = 0; j < 256; j += 16) {
        f32x4 x0 = *(const f32x4*)(xp + j);
        f32x4 x1 = *(const f32x4*)(xp + j + 4);
        f32x4 x2 = *(const f32x4*)(xp + j + 8);
        f32x4 x3 = *(const f32x4*)(xp + j + 12);
        f32x4 s0 = *(const f32x4*)(sp + j);
        f32x4 s1 = *(const f32x4*)(sp + j + 4);
        f32x4 s2 = *(const f32x4*)(sp + j + 8);
        f32x4 s3 = *(const f32x4*)(sp + j + 12);
#pragma unroll
        for (int k = 0; k < 4; ++k) {
            pa = fma((double)x0[k], (double)s0[k], pa);
            pb = fma((double)x1[k], (double)s1[k], pb);
            pc = fma((double)x2[k], (double)s2[k], pc);
            pd = fma((double)x3[k], (double)s3[k], pd);
        }
    }
    double p = (pa + pb) + (pc + pd);
    p += __shfl_xor(p, 4);                          // combine the two K-halves
    if (seg == 0) sc[tok][e] = p;
    __syncthreads();

    if (tid < 4) {
        int t = tb + tid;
        unsigned mask = 0;
        u32 eids = 0;
        f32x4 gs;
        for (int k = 0; k < TK; ++k) {
            double best = -1e300; int be = 0;
            for (int ee = 0; ee < NE; ++ee) {
                double v = sc[tid][ee];
                if (!((mask >> ee) & 1u) && v > best) { best = v; be = ee; }
            }
            mask |= 1u << be;
            eids |= (u32)be << (8 * k);
            gs[k] = 1.0f / (1.0f + __expf(-(float)best));
        }
        route_e[t] = eids;
        *(f32x4*)&route_g[4 * t] = gs;
    }
}

// ---------------- build lists: 1 block per expert, LDS counter only ----------------
__global__ __launch_bounds__(256) void build_kernel(const u32* __restrict__ route_e,
                                                    const float* __restrict__ route_g,
                                                    int* __restrict__ counts,
                                                    int* __restrict__ tok_list,
                                                    float* __restrict__ gate_list) {
    int e = blockIdx.x;
    __shared__ int cnt;
    if (threadIdx.x == 0) cnt = 0;
    __syncthreads();
#pragma unroll
    for (int rep = 0; rep < NTOK / 256; ++rep) {
        int t = rep * 256 + threadIdx.x;            // coalesced u32 load
        u32 eid = route_e[t];
        int k = -1;
        if ((eid & 255u) == (u32)e) k = 0;
        else if (((eid >> 8) & 255u) == (u32)e) k = 1;
        else if (((eid >> 16) & 255u) == (u32)e) k = 2;
        else if (((eid >> 24) & 255u) == (u32)e) k = 3;
        if (k >= 0) {
            int pos = atomicAdd(&cnt, 1);           // LDS atomic: block-local, cheap
            tok_list[e * NTOK + pos]  = (k << 16) | t;
            gate_list[e * NTOK + pos] = route_g[4 * t + k];
        }
    }
    __syncthreads();
    if (threadIdx.x == 0) counts[e] = cnt;
}

// ---------------- fused expert MLP ----------------
// XCD-aware: block b serves expert group (b&7) -> per-XCD weight set = 1 MB (L2-resident).
// GEMM1 waves 2x2 (rows x cols) paired-k dbuf; GEMM2 wave owns 128 cols; epilogue via
// LDS transpose (Ct) -> 1 KB contiguous row stores.
__global__ __launch_bounds__(256, 2) void moe_mlp_kernel(const u16* __restrict__ xbf,
                                                         const u16* __restrict__ wf1,
                                                         const u16* __restrict__ wf2,
                                                         const int* __restrict__ counts,
                                                         const int* __restrict__ tok_list,
                                                         const float* __restrict__ gate_list,
                                                         u16* __restrict__ part,
                                                         float* __restrict__ out,
                                                         int use_part) {
    __shared__ int   s_cnt[NE];
    __shared__ int   s_ent[64];
    __shared__ float s_gate[64];
    __shared__ __align__(16) u16 Hm[64][136];       // 272B stride
    __shared__ __align__(16) u16 Ct[32][520];       // 1040B stride

    int tid = threadIdx.x;
    if (tid < NE) s_cnt[tid] = counts[tid];
    __syncthreads();

    int b = blockIdx.x;
    int xcd = b & 7, idx = b >> 3;
    int e = -1, t = 0, rows = 0, pre = 0;
#pragma unroll
    for (int j = 0; j < 4; ++j) {                   // experts xcd, xcd+8, xcd+16, xcd+24
        int ee = xcd + 8 * j;
        int cc = s_cnt[ee];
        int nt = (cc + 63) >> 6;
        if (e < 0 && idx < pre + nt) { e = ee; t = idx - pre; rows = cc - t * 64; if (rows > 64) rows = 64; }
        pre += nt;
    }
    if (e < 0) return;

    if (tid < 64) {
        int base = e * NTOK + t * 64;
        bool val = tid < rows;
        s_ent[tid]  = tok_list[base + (val ? tid : 0)];
        s_gate[tid] = val ? gate_list[base + tid] : 0.0f;
    }
    __syncthreads();

    int wv = tid >> 6, lane = tid & 63, m = lane & 15, q = lane >> 4;
    int r = wv >> 1, c = wv & 1;                    // GEMM1: rows 32r..+32, cols 64c..+64
    const u16* w1f = wf1 + (size_t)e * (128 * 512);
    const u16* w2f = wf2 + (size_t)e * (128 * 512);

    const u16* a0 = xbf + (size_t)(s_ent[32 * r + m] & 0xFFFF) * DM + q * 8;
    const u16* a1 = xbf + (size_t)(s_ent[32 * r + 16 + m] & 0xFFFF) * DM + q * 8;

    // GEMM1: k-steps in pairs, double-buffered
    short8 ab[2][2][2];
    short8 bb[2][2][4];
#pragma unroll
    for (int kk = 0; kk < 2; ++kk) {
        ab[0][kk][0] = *(const short8*)(a0 + 32 * kk);
        ab[0][kk][1] = *(const short8*)(a1 + 32 * kk);
        const u16* bp = w1f + (size_t)kk * 4096 + (size_t)(4 * c) * 512 + lane * 8;
#pragma unroll
        for (int n = 0; n < 4; ++n) bb[0][kk][n] = *(const short8*)(bp + n * 512);
    }
    f32x4 acc[2][4];
#pragma unroll
    for (int i = 0; i < 2; ++i)
#pragma unroll
        for (int n = 0; n < 4; ++n) acc[i][n] = (f32x4){0.f, 0.f, 0.f, 0.f};

#pragma unroll
    for (int kp = 0; kp < 8; ++kp) {
        int cur = kp & 1, nxt = cur ^ 1;
        if (kp < 7) {
            int ks0 = 2 * (kp + 1);
#pragma unroll
            for (int kk = 0; kk < 2; ++kk) {
                ab[nxt][kk][0] = *(const short8*)(a0 + 32 * (ks0 + kk));
                ab[nxt][kk][1] = *(const short8*)(a1 + 32 * (ks0 + kk));
                const u16* bp = w1f + (size_t)(ks0 + kk) * 4096 + (size_t)(4 * c) * 512 + lane * 8;
#pragma unroll
                for (int n = 0; n < 4; ++n) bb[nxt][kk][n] = *(const short8*)(bp + n * 512);
            }
        }
#pragma unroll
        for (int kk = 0; kk < 2; ++kk)
#pragma unroll
            for (int i = 0; i < 2; ++i)
#pragma unroll
                for (int n = 0; n < 4; ++n)
                    acc[i][n] = __builtin_amdgcn_mfma_f32_16x16x32_bf16(ab[cur][kk][i],
                                                                        bb[cur][kk][n],
                                                                        acc[i][n], 0, 0, 0);
    }

    // relu * gate -> Hm
#pragma unroll
    for (int i = 0; i < 2; ++i) {
        int rb = 32 * r + 16 * i + q * 4;
#pragma unroll
        for (int n = 0; n < 4; ++n)
#pragma unroll
            for (int rr = 0; rr < 4; ++rr)
                Hm[rb + rr][64 * c + 16 * n + m] =
                    f2bf(fmaxf(acc[i][n][rr], 0.f) * s_gate[rb + rr]);
    }

    // GEMM2: wave owns cols [128*wv, +128); all 32 B-frags issued before barrier
    short8 cb[4][8];
#pragma unroll
    for (int ks = 0; ks < 4; ++ks) {
        const u16* bp = w2f + (size_t)(ks * 32 + wv * 8) * 512 + lane * 8;
#pragma unroll
        for (int n = 0; n < 8; ++n) cb[ks][n] = *(const short8*)(bp + n * 512);
    }
    __syncthreads();                                // Hm ready

#pragma unroll
    for (int half = 0; half < 2; ++half) {
        f32x4 acc2[2][8];
#pragma unroll
        for (int i = 0; i < 2; ++i)
#pragma unroll
            for (int n = 0; n < 8; ++n) acc2[i][n] = (f32x4){0.f, 0.f, 0.f, 0.f};
#pragma unroll
        for (int ks = 0; ks < 4; ++ks) {
            short8 h0 = *(const short8*)&Hm[32 * half + m][32 * ks + q * 8];
            short8 h1 = *(const short8*)&Hm[32 * half + 16 + m][32 * ks + q * 8];
#pragma unroll
            for (int n = 0; n < 8; ++n) {
                acc2[0][n] = __builtin_amdgcn_mfma_f32_16x16x32_bf16(h0, cb[ks][n], acc2[0][n], 0, 0, 0);
                acc2[1][n] = __builtin_amdgcn_mfma_f32_16x16x32_bf16(h1, cb[ks][n], acc2[1][n], 0, 0, 0);
            }
        }
        // C-layout -> LDS transpose (each wave writes its 128-col stripe)
#pragma unroll
        for (int i = 0; i < 2; ++i) {
            int rb = 16 * i + q * 4;                // row within half tile
#pragma unroll
            for (int n = 0; n < 8; ++n)
#pragma unroll
                for (int rr = 0; rr < 4; ++rr)
                    Ct[rb + rr][128 * wv + 16 * n + m] = f2bf(acc2[i][n][rr]);
        }
        __syncthreads();                            // Ct complete
        // contiguous row stores: wave handles full 512-col rows
#pragma unroll
        for (int rep = 0; rep < 8; ++rep) {
            int rl = rep * 4 + wv;                  // 0..31
            int rt = 32 * half + rl;
            u16x8 v = *(const u16x8*)&Ct[rl][lane * 8];
            if (rt < rows) {
                int en = s_ent[rt];
                int tk = en & 0xFFFF, sl2 = en >> 16;
                if (use_part) {
                    *(u16x8*)(part + ((size_t)sl2 * NTOK + tk) * DM + lane * 8) = v;
                } else {
                    float* op = out + (size_t)tk * DM + lane * 8;
#pragma unroll
                    for (int j = 0; j < 8; ++j) atomicAdd(&op[j], bf2f(v[j]));
                }
            }
        }
        __syncthreads();                            // Ct reusable
    }
}

// ---------------- combine: out[t][c] = sum_k part[k][t][c] ----------------
__global__ __launch_bounds__(256) void combine_kernel(const u16* __restrict__ part,
                                                      float* __restrict__ out) {
    size_t off = ((size_t)blockIdx.x * 256 + threadIdx.x) * 8;
    float s[8] = {0, 0, 0, 0, 0, 0, 0, 0};
#pragma unroll
    for (int k = 0; k < TK; ++k) {
        u16x8 p = *(const u16x8*)(part + (size_t)k * NTOK * DM + off);
#pragma unroll
        for (int j = 0; j < 8; ++j) s[j] += bf2f(p[j]);
    }
    *(f32x4*)(out + off)     = (f32x4){s[0], s[1], s[2], s[3]};
    *(f32x4*)(out + off + 4) = (f32x4){s[4], s[5], s[6], s[7]};
}

extern "C" void kernel_launch(void* const* d_in, const int* in_sizes, int n_in,
                              void* d_out, int out_size, void* d_ws, size_t ws_size,
                              hipStream_t stream) {
    const float* x   = (const float*)d_in[0];   // [N, D]
    const float* sel = (const float*)d_in[1];   // [E, D]
    const float* w1  = (const float*)d_in[2];   // [E, D, H]
    const float* w2  = (const float*)d_in[3];   // [E, H, D]
    float* out = (float*)d_out;                 // [N, D]

    char* ws = (char*)d_ws;
    int*   counts    = (int*)(ws);                                   // 256 B
    u32*   route_e   = (u32*)(ws + 256);                             // 16 KB
    float* route_g   = (float*)(ws + 256 + (size_t)NTOK * 4);        // 64 KB
    char*  ws2       = ws + 256 + (size_t)NTOK * 20;
    int*   tok_list  = (int*)(ws2);                                  // 512 KB
    float* gate_list = (float*)(ws2 + (size_t)NE * NTOK * 4);        // 512 KB
    u16*   xbf  = (u16*)(ws2 + (size_t)NE * NTOK * 8);               // 4 MB
    u16*   wf1  = xbf + (size_t)NTOK * DM;                           // 4 MB
    u16*   wf2  = wf1 + (size_t)NE * HD * DM;                        // 4 MB
    u16*   part = wf2 + (size_t)NE * HD * DM;                        // 16.8 MB (optional)

    size_t need = 256 + (size_t)NTOK * 20 + (size_t)NE * NTOK * 8
                + (size_t)NTOK * DM * 2 + 2 * (size_t)NE * HD * DM * 2
                + (size_t)TK * NTOK * DM * 2;
    int use_part = (ws_size >= need) ? 1 : 0;

    if (!use_part)
        hipMemsetAsync(d_out, 0, (size_t)NTOK * DM * sizeof(float), stream);

    swizzle_kernel<<<1024, 256, 0, stream>>>(w1, w2, wf1, wf2);
    router_kernel<<<NTOK / 4, 256, 0, stream>>>(x, sel, route_e, route_g, xbf);
    build_kernel<<<NE, 256, 0, stream>>>(route_e, route_g, counts, tok_list, gate_list);
    // XCD-aware grid: 8 groups x 260 worst-case tiles; empty blocks exit cheaply
    moe_mlp_kernel<<<2080, 256, 0, stream>>>(xbf, wf1, wf2, counts, tok_list, gate_list,
                                             part, out, use_part);
    if (use_part)
        combine_kernel<<<NTOK * DM / 8 / 256, 256, 0, stream>>>(part, out);
}

// Round 11
// 120.230 us; speedup vs baseline: 1.3698x; 1.1070x over previous
//
#include <hip/hip_runtime.h>
#include <hip/hip_bf16.h>

// Problem constants: N tokens, D d_model, E experts, H hidden, K top-k
#define NTOK 4096
#define DM   512
#define NE   32
#define HD   128
#define TK   4

typedef unsigned short u16;
typedef unsigned int   u32;
typedef u16   u16x4 __attribute__((ext_vector_type(4)));
typedef u16   u16x8 __attribute__((ext_vector_type(8)));
typedef short short8 __attribute__((ext_vector_type(8)));
typedef float f32x4 __attribute__((ext_vector_type(4)));

__device__ __forceinline__ u16 f2bf(float f) {
    union { float f; u32 u; } v; v.f = f;
    return (u16)((v.u + 0x7FFFu + ((v.u >> 16) & 1u)) >> 16);   // RNE
}
__device__ __forceinline__ float bf2f(u16 h) {
    union { u32 u; float f; } v; v.u = ((u32)h) << 16; return v.f;
}

// ---------------- fused prep ----------------
// blocks [0,1024):     router, 4 tokens/block (fp64; per-expert padded-line atomics)
// blocks [1024,2048):  weight swizzle fp32 -> bf16 fragment-major
//   frag[wl][lane][j] = in[e][32*ks + (lane>>4)*8 + j][16*nt + (lane&15)]
__global__ __launch_bounds__(256) void prep_kernel(const float* __restrict__ x,
                                                   const float* __restrict__ sel,
                                                   const float* __restrict__ w1,
                                                   const float* __restrict__ w2,
                                                   int* __restrict__ counts_pad,
                                                   int* __restrict__ tok_list,
                                                   float* __restrict__ gate_list,
                                                   u16* __restrict__ xbf,
                                                   u16* __restrict__ wf1,
                                                   u16* __restrict__ wf2) {
    // small LDS only (router branch) so swizzle blocks keep high occupancy
    __shared__ float  xs[4][520];
    __shared__ double sc[4][33];
    int tid = threadIdx.x;
    int wv = tid >> 6, lane = tid & 63;

    if (blockIdx.x >= 1024) {
        // ---- weight swizzle: 2 fragments per wave ----
        int m = lane & 15, q = lane >> 4;
        int f0 = ((blockIdx.x - 1024) * 4 + wv) * 2;
        const float* in[2]; u16* outp[2]; int Nd[2];
#pragma unroll
        for (int u = 0; u < 2; ++u) {
            int w = f0 + u;
            if (w < 4096) {
                int e = w >> 7, rem = w & 127, ks = rem >> 3, nt = rem & 7;
                in[u] = w1 + (size_t)e * DM * HD + (size_t)(32 * ks + q * 8) * HD + 16 * nt + m;
                Nd[u] = HD;
                outp[u] = wf1 + (size_t)w * 512 + lane * 8;
            } else {
                int wl = w - 4096, e = wl >> 7, rem = wl & 127, ks = rem >> 5, nt = rem & 31;
                in[u] = w2 + (size_t)e * HD * DM + (size_t)(32 * ks + q * 8) * DM + 16 * nt + m;
                Nd[u] = DM;
                outp[u] = wf2 + (size_t)wl * 512 + lane * 8;
            }
        }
        float v[2][8];
#pragma unroll
        for (int u = 0; u < 2; ++u)
#pragma unroll
            for (int j = 0; j < 8; ++j) v[u][j] = in[u][(size_t)j * Nd[u]];
#pragma unroll
        for (int u = 0; u < 2; ++u) {
            u16x8 h;
#pragma unroll
            for (int j = 0; j < 8; ++j) h[j] = f2bf(v[u][j]);
            *(u16x8*)outp[u] = h;
        }
        return;
    }

    // ---- router: 4 tokens/block, blocks [0,1024) cover all 4096 tokens ----
    int tb = blockIdx.x * 4;
#pragma unroll
    for (int rep = 0; rep < 2; ++rep) {
        int idx = (rep * 256 + tid) * 4;            // element in 4x512 tile
        int row = idx >> 9, col = idx & 511;
        f32x4 v = *(const f32x4*)(x + (size_t)(tb + row) * DM + col);
        *(f32x4*)&xs[row][col] = v;
        u16x4 h;
#pragma unroll
        for (int j = 0; j < 4; ++j) h[j] = f2bf(v[j]);
        *(u16x4*)(xbf + (size_t)(tb + row) * DM + col) = h;
    }
    __syncthreads();

    // thread: tok = tid&3, seg = (tid>>2)&1, e = tid>>3 ; 256-long fp64 dot, 4 chains
    int tok = tid & 3, seg = (tid >> 2) & 1, e = tid >> 3;
    const float* sp = sel + (size_t)e * DM + seg * 256;
    const float* xp = &xs[tok][seg * 256];
    double pa = 0.0, pb = 0.0, pc = 0.0, pd = 0.0;
#pragma unroll 4
    for (int j = 0; j < 256; j += 16) {
        f32x4 x0 = *(const f32x4*)(xp + j);
        f32x4 x1 = *(const f32x4*)(xp + j + 4);
        f32x4 x2 = *(const f32x4*)(xp + j + 8);
        f32x4 x3 = *(const f32x4*)(xp + j + 12);
        f32x4 s0 = *(const f32x4*)(sp + j);
        f32x4 s1 = *(const f32x4*)(sp + j + 4);
        f32x4 s2 = *(const f32x4*)(sp + j + 8);
        f32x4 s3 = *(const f32x4*)(sp + j + 12);
#pragma unroll
        for (int k = 0; k < 4; ++k) {
            pa = fma((double)x0[k], (double)s0[k], pa);
            pb = fma((double)x1[k], (double)s1[k], pb);
            pc = fma((double)x2[k], (double)s2[k], pc);
            pd = fma((double)x3[k], (double)s3[k], pd);
        }
    }
    double p = (pa + pb) + (pc + pd);
    p += __shfl_xor(p, 4);                          // combine the two K-halves
    if (seg == 0) sc[tok][e] = p;
    __syncthreads();

    if (tid < 4) {
        int t = tb + tid;
        unsigned mask = 0;
        for (int k = 0; k < TK; ++k) {
            double best = -1e300; int be = 0;
            for (int ee = 0; ee < NE; ++ee) {
                double v = sc[tid][ee];
                if (!((mask >> ee) & 1u) && v > best) { best = v; be = ee; }
            }
            mask |= 1u << be;
            float gate = 1.0f / (1.0f + __expf(-(float)best));
            int pos = atomicAdd(&counts_pad[32 * be], 1);    // own 128-B line per expert
            tok_list[be * NTOK + pos]  = (k << 16) | t;
            gate_list[be * NTOK + pos] = gate;
        }
    }
}

// ---------------- fused expert MLP ----------------
// XCD-aware: block b serves expert group (b&7) -> per-XCD weight set = 1 MB (L2-resident).
// GEMM1 waves 2x2 (rows x cols) paired-k dbuf; GEMM2 wave owns 128 cols; epilogue via
// LDS transpose (Ct) -> 1 KB contiguous row stores.
__global__ __launch_bounds__(256, 2) void moe_mlp_kernel(const u16* __restrict__ xbf,
                                                         const u16* __restrict__ wf1,
                                                         const u16* __restrict__ wf2,
                                                         const int* __restrict__ counts_pad,
                                                         const int* __restrict__ tok_list,
                                                         const float* __restrict__ gate_list,
                                                         u16* __restrict__ part,
                                                         float* __restrict__ out,
                                                         int use_part) {
    __shared__ int   s_cnt[NE];
    __shared__ int   s_ent[64];
    __shared__ float s_gate[64];
    __shared__ __align__(16) u16 Hm[64][136];       // 272B stride
    __shared__ __align__(16) u16 Ct[32][520];       // 1040B stride

    int tid = threadIdx.x;
    if (tid < NE) s_cnt[tid] = counts_pad[32 * tid];
    __syncthreads();

    int b = blockIdx.x;
    int xcd = b & 7, idx = b >> 3;
    int e = -1, t = 0, rows = 0, pre = 0;
#pragma unroll
    for (int j = 0; j < 4; ++j) {                   // experts xcd, xcd+8, xcd+16, xcd+24
        int ee = xcd + 8 * j;
        int cc = s_cnt[ee];
        int nt = (cc + 63) >> 6;
        if (e < 0 && idx < pre + nt) { e = ee; t = idx - pre; rows = cc - t * 64; if (rows > 64) rows = 64; }
        pre += nt;
    }
    if (e < 0) return;

    if (tid < 64) {
        int base = e * NTOK + t * 64;
        bool val = tid < rows;
        s_ent[tid]  = tok_list[base + (val ? tid : 0)];
        s_gate[tid] = val ? gate_list[base + tid] : 0.0f;
    }
    __syncthreads();

    int wv = tid >> 6, lane = tid & 63, m = lane & 15, q = lane >> 4;
    int r = wv >> 1, c = wv & 1;                    // GEMM1: rows 32r..+32, cols 64c..+64
    const u16* w1f = wf1 + (size_t)e * (128 * 512);
    const u16* w2f = wf2 + (size_t)e * (128 * 512);

    const u16* a0 = xbf + (size_t)(s_ent[32 * r + m] & 0xFFFF) * DM + q * 8;
    const u16* a1 = xbf + (size_t)(s_ent[32 * r + 16 + m] & 0xFFFF) * DM + q * 8;

    // GEMM1: k-steps in pairs, double-buffered
    short8 ab[2][2][2];
    short8 bb[2][2][4];
#pragma unroll
    for (int kk = 0; kk < 2; ++kk) {
        ab[0][kk][0] = *(const short8*)(a0 + 32 * kk);
        ab[0][kk][1] = *(const short8*)(a1 + 32 * kk);
        const u16* bp = w1f + (size_t)kk * 4096 + (size_t)(4 * c) * 512 + lane * 8;
#pragma unroll
        for (int n = 0; n < 4; ++n) bb[0][kk][n] = *(const short8*)(bp + n * 512);
    }
    f32x4 acc[2][4];
#pragma unroll
    for (int i = 0; i < 2; ++i)
#pragma unroll
        for (int n = 0; n < 4; ++n) acc[i][n] = (f32x4){0.f, 0.f, 0.f, 0.f};

#pragma unroll
    for (int kp = 0; kp < 8; ++kp) {
        int cur = kp & 1, nxt = cur ^ 1;
        if (kp < 7) {
            int ks0 = 2 * (kp + 1);
#pragma unroll
            for (int kk = 0; kk < 2; ++kk) {
                ab[nxt][kk][0] = *(const short8*)(a0 + 32 * (ks0 + kk));
                ab[nxt][kk][1] = *(const short8*)(a1 + 32 * (ks0 + kk));
                const u16* bp = w1f + (size_t)(ks0 + kk) * 4096 + (size_t)(4 * c) * 512 + lane * 8;
#pragma unroll
                for (int n = 0; n < 4; ++n) bb[nxt][kk][n] = *(const short8*)(bp + n * 512);
            }
        }
#pragma unroll
        for (int kk = 0; kk < 2; ++kk)
#pragma unroll
            for (int i = 0; i < 2; ++i)
#pragma unroll
                for (int n = 0; n < 4; ++n)
                    acc[i][n] = __builtin_amdgcn_mfma_f32_16x16x32_bf16(ab[cur][kk][i],
                                                                        bb[cur][kk][n],
                                                                        acc[i][n], 0, 0, 0);
    }

    // relu * gate -> Hm
#pragma unroll
    for (int i = 0; i < 2; ++i) {
        int rb = 32 * r + 16 * i + q * 4;
#pragma unroll
        for (int n = 0; n < 4; ++n)
#pragma unroll
            for (int rr = 0; rr < 4; ++rr)
                Hm[rb + rr][64 * c + 16 * n + m] =
                    f2bf(fmaxf(acc[i][n][rr], 0.f) * s_gate[rb + rr]);
    }

    // GEMM2: wave owns cols [128*wv, +128); all 32 B-frags issued before barrier
    short8 cb[4][8];
#pragma unroll
    for (int ks = 0; ks < 4; ++ks) {
        const u16* bp = w2f + (size_t)(ks * 32 + wv * 8) * 512 + lane * 8;
#pragma unroll
        for (int n = 0; n < 8; ++n) cb[ks][n] = *(const short8*)(bp + n * 512);
    }
    __syncthreads();                                // Hm ready

#pragma unroll
    for (int half = 0; half < 2; ++half) {
        f32x4 acc2[2][8];
#pragma unroll
        for (int i = 0; i < 2; ++i)
#pragma unroll
            for (int n = 0; n < 8; ++n) acc2[i][n] = (f32x4){0.f, 0.f, 0.f, 0.f};
#pragma unroll
        for (int ks = 0; ks < 4; ++ks) {
            short8 h0 = *(const short8*)&Hm[32 * half + m][32 * ks + q * 8];
            short8 h1 = *(const short8*)&Hm[32 * half + 16 + m][32 * ks + q * 8];
#pragma unroll
            for (int n = 0; n < 8; ++n) {
                acc2[0][n] = __builtin_amdgcn_mfma_f32_16x16x32_bf16(h0, cb[ks][n], acc2[0][n], 0, 0, 0);
                acc2[1][n] = __builtin_amdgcn_mfma_f32_16x16x32_bf16(h1, cb[ks][n], acc2[1][n], 0, 0, 0);
            }
        }
        // C-layout -> LDS transpose (each wave writes its 128-col stripe)
#pragma unroll
        for (int i = 0; i < 2; ++i) {
            int rb = 16 * i + q * 4;                // row within half tile
#pragma unroll
            for (int n = 0; n < 8; ++n)
#pragma unroll
                for (int rr = 0; rr < 4; ++rr)
                    Ct[rb + rr][128 * wv + 16 * n + m] = f2bf(acc2[i][n][rr]);
        }
        __syncthreads();                            // Ct complete
        // contiguous row stores: wave handles full 512-col rows
#pragma unroll
        for (int rep = 0; rep < 8; ++rep) {
            int rl = rep * 4 + wv;                  // 0..31
            int rt = 32 * half + rl;
            u16x8 v = *(const u16x8*)&Ct[rl][lane * 8];
            if (rt < rows) {
                int en = s_ent[rt];
                int tk = en & 0xFFFF, sl2 = en >> 16;
                if (use_part) {
                    *(u16x8*)(part + ((size_t)sl2 * NTOK + tk) * DM + lane * 8) = v;
                } else {
                    float* op = out + (size_t)tk * DM + lane * 8;
#pragma unroll
                    for (int j = 0; j < 8; ++j) atomicAdd(&op[j], bf2f(v[j]));
                }
            }
        }
        __syncthreads();                            // Ct reusable
    }
}

// ---------------- combine: out[t][c] = sum_k part[k][t][c] ----------------
__global__ __launch_bounds__(256) void combine_kernel(const u16* __restrict__ part,
                                                      float* __restrict__ out) {
    size_t off = ((size_t)blockIdx.x * 256 + threadIdx.x) * 8;
    float s[8] = {0, 0, 0, 0, 0, 0, 0, 0};
#pragma unroll
    for (int k = 0; k < TK; ++k) {
        u16x8 p = *(const u16x8*)(part + (size_t)k * NTOK * DM + off);
#pragma unroll
        for (int j = 0; j < 8; ++j) s[j] += bf2f(p[j]);
    }
    *(f32x4*)(out + off)     = (f32x4){s[0], s[1], s[2], s[3]};
    *(f32x4*)(out + off + 4) = (f32x4){s[4], s[5], s[6], s[7]};
}

extern "C" void kernel_launch(void* const* d_in, const int* in_sizes, int n_in,
                              void* d_out, int out_size, void* d_ws, size_t ws_size,
                              hipStream_t stream) {
    const float* x   = (const float*)d_in[0];   // [N, D]
    const float* sel = (const float*)d_in[1];   // [E, D]
    const float* w1  = (const float*)d_in[2];   // [E, D, H]
    const float* w2  = (const float*)d_in[3];   // [E, H, D]
    float* out = (float*)d_out;                 // [N, D]

    char* ws = (char*)d_ws;
    int*   counts_pad = (int*)(ws);                                  // 4 KB (32 lines)
    int*   tok_list   = (int*)(ws + 4096);                           // 512 KB
    float* gate_list  = (float*)(ws + 4096 + (size_t)NE * NTOK * 4); // 512 KB
    u16*   xbf  = (u16*)(ws + 4096 + (size_t)NE * NTOK * 8);         // 4 MB
    u16*   wf1  = xbf + (size_t)NTOK * DM;                           // 4 MB
    u16*   wf2  = wf1 + (size_t)NE * HD * DM;                        // 4 MB
    u16*   part = wf2 + (size_t)NE * HD * DM;                        // 16.8 MB (optional)

    size_t need = 4096 + (size_t)NE * NTOK * 8 + (size_t)NTOK * DM * 2
                + 2 * (size_t)NE * HD * DM * 2 + (size_t)TK * NTOK * DM * 2;
    int use_part = (ws_size >= need) ? 1 : 0;

    hipMemsetAsync(counts_pad, 0, 4096, stream);
    if (!use_part)
        hipMemsetAsync(d_out, 0, (size_t)NTOK * DM * sizeof(float), stream);

    // blocks [0,1024) router (4 tok/block -> all 4096 tokens); [1024,2048) swizzle
    prep_kernel<<<2048, 256, 0, stream>>>(x, sel, w1, w2, counts_pad, tok_list,
                                          gate_list, xbf, wf1, wf2);
    // XCD-aware grid: 8 groups x 260 worst-case tiles; empty blocks exit cheaply
    moe_mlp_kernel<<<2080, 256, 0, stream>>>(xbf, wf1, wf2, counts_pad, tok_list,
                                             gate_list, part, out, use_part);
    if (use_part)
        combine_kernel<<<NTOK * DM / 8 / 256, 256, 0, stream>>>(part, out);
}